// Round 9
// baseline (91.786 us; speedup 1.0000x reference)
//
#include <hip/hip_runtime.h>
#include <stdint.h>

#define DIM 512
#define DH  64
#define NH  8
#define NKV 2
#define NB  4
#define NS  2048
#define TAB (NS*32)

typedef __attribute__((ext_vector_type(8))) short short8;
typedef __attribute__((ext_vector_type(4))) short s16x4;
typedef __attribute__((ext_vector_type(4))) float f32x4;
typedef __attribute__((ext_vector_type(16))) float f32x16;
typedef __attribute__((ext_vector_type(2))) unsigned uint2v;
typedef __attribute__((ext_vector_type(4))) unsigned uint4v;

__device__ __forceinline__ unsigned short f2bf(float f) {
  union { float f; unsigned u; } v; v.f = f;
  return (unsigned short)((v.u + 0x7fffu + ((v.u >> 16) & 1u)) >> 16);
}
__device__ __forceinline__ float bf2f(unsigned short b) {
  union { unsigned u; float f; } v; v.u = ((unsigned)b) << 16;
  return v.f;
}
__device__ __forceinline__ unsigned cvt_pk_bf16(float a, float b) {
  unsigned r;
  asm("v_cvt_pk_bf16_f32 %0, %1, %2" : "=v"(r) : "v"(a), "v"(b));
  return r;
}
__device__ __forceinline__ float exp2_raw(float x) {
  float r;
  asm("v_exp_f32 %0, %1" : "=v"(r) : "v"(x));
  return r;
}

// ---------- LayerNorm + transpose, ONE PASS: x (b,512,2048) f32 -> xn (b*2048,512) bf16
__global__ __launch_bounds__(256) void ln_kernel(const float* __restrict__ x,
    const float* __restrict__ gamma, const float* __restrict__ beta,
    unsigned short* __restrict__ xn) {
  const int b = blockIdx.y;
  const int n0 = blockIdx.x * 32;
  const int tid = threadIdx.x;
  const int nl = tid & 31, grp = tid >> 5;
  const float* xb = x + (size_t)b * DIM * NS + (size_t)grp * 64 * NS + n0 + nl;
  float v[64];
  float s = 0.f, s2 = 0.f;
  #pragma unroll
  for (int i = 0; i < 64; ++i) {
    v[i] = xb[(size_t)i * NS];
    s += v[i]; s2 += v[i] * v[i];
  }
  __shared__ float sm[8][32], sq[8][32], mu_s[32], rs_s[32];
  sm[grp][nl] = s; sq[grp][nl] = s2;
  __syncthreads();
  if (tid < 32) {
    float ts = 0.f, ts2 = 0.f;
    #pragma unroll
    for (int g = 0; g < 8; ++g) { ts += sm[g][tid]; ts2 += sq[g][tid]; }
    float mu = ts * (1.f/512.f);
    float var = ts2 * (1.f/512.f) - mu*mu;
    mu_s[tid] = mu; rs_s[tid] = rsqrtf(var + 1e-5f);
  }
  __syncthreads();
  const float mu = mu_s[nl], rs = rs_s[nl];
  unsigned short* dst = &xn[((size_t)(b*NS + n0 + nl))*DIM + grp*64];
  #pragma unroll
  for (int c = 0; c < 8; ++c) {
    short8 o;
    #pragma unroll
    for (int j = 0; j < 8; ++j) {
      int d = grp*64 + c*8 + j;
      o[j] = (short)f2bf((v[c*8 + j] - mu) * rs * gamma[d] + beta[d]);
    }
    *(short8*)&dst[c*8] = o;
  }
}

// ---------- prep: weight transpose+convert (blocks 0..159) + rotary tables (160..167)
__global__ __launch_bounds__(256) void prep_kernel(const float* __restrict__ Wq,
    const float* __restrict__ Wkv, const float* __restrict__ Wout,
    unsigned short* __restrict__ Wqkvt, unsigned short* __restrict__ Woutt,
    float* __restrict__ tabs) {
  __shared__ float t[64][65];
  const int id = blockIdx.x;
  const int tid = threadIdx.x;
  if (id >= 160) {               // ---- rotary tables
    int base = (id - 160) * 256 + tid;
    #pragma unroll 4
    for (int ii = 0; ii < 32; ++ii) {
      int tix = base + ii * 2048;
      int pos = tix >> 5, i = tix & 31;
      float inv = exp2f(-(float)i * (13.287712379549449f / 32.f));  // 10000^(-2i/64)
      float ang = (float)pos * inv;
      float sv, cv; sincosf(ang, &sv, &cv);
      float bse = ((float)(2*i) + 25.6f) / 89.6f;
      float power = ((float)pos - 1024.f) / 4096.f;
      float sc = exp2f(power * log2f(bse));
      tabs[tix]         = cv;
      tabs[TAB + tix]   = sv;
      tabs[2*TAB + tix] = sc * 0.125f * 1.4426950408889634f;  // qscale*1/sqrt(dh)*log2e
      tabs[3*TAB + tix] = 1.f / sc;                           // k scale
    }
    return;
  }
  const float* src; int W, k0, c0; unsigned short* dst; int drow0;
  if (id < 64)      { src = Wq;  W = 512; k0 = (id>>3)*64;        c0 = (id&7)*64;        dst = Wqkvt; drow0 = c0; }
  else if (id < 96) { int i2 = id-64; src = Wkv; W = 256; k0 = (i2>>2)*64; c0 = (i2&3)*64; dst = Wqkvt; drow0 = 512 + c0; }
  else              { int i3 = id-96; src = Wout; W = 512; k0 = (i3>>3)*64; c0 = (i3&7)*64; dst = Woutt; drow0 = c0; }
  #pragma unroll 4
  for (int it = 0; it < 16; ++it) {
    int row = it*4 + (tid>>6), col = tid & 63;
    t[row][col] = src[(size_t)(k0+row)*W + c0 + col];
  }
  __syncthreads();
  #pragma unroll 4
  for (int it = 0; it < 16; ++it) {
    int row = it*4 + (tid>>6), col = tid & 63;
    dst[(size_t)(drow0 + row)*512 + k0 + col] = f2bf(t[col][row]);
  }
}

// ---------- QKV GEMM, 64x128 tile (wave 32x64), dbuf single-barrier; fused rotary; V^T store
__global__ __launch_bounds__(256, 3) void qkv_kernel(const unsigned short* __restrict__ A,
    const unsigned short* __restrict__ Bt, const float* __restrict__ tabs,
    unsigned short* __restrict__ q, unsigned short* __restrict__ k,
    unsigned short* __restrict__ v) {
  __shared__ __align__(16) short As[2][64][40];
  __shared__ __align__(16) short Bs[2][128][40];
  const int m0 = blockIdx.x * 64, ntile = blockIdx.y, n0 = ntile * 128;
  const int tid = threadIdx.x, w = tid >> 6, lane = tid & 63;
  const int wr = w >> 1, wc = w & 1;
  f32x4 acc[2][4];
  #pragma unroll
  for (int i = 0; i < 2; ++i)
    #pragma unroll
    for (int j = 0; j < 4; ++j) acc[i][j] = (f32x4){0.f,0.f,0.f,0.f};
  const int rA = tid >> 2, c8 = (tid & 3) * 8;
  const unsigned short* Ar0 = &A[(size_t)(m0 + rA)*DIM + c8];
  const unsigned short* Br0 = &Bt[(size_t)(n0 + rA)*DIM + c8];
  const unsigned short* Br1 = &Bt[(size_t)(n0 + 64 + rA)*DIM + c8];
  *(short8*)&As[0][rA][c8]      = *(const short8*)Ar0;
  *(short8*)&Bs[0][rA][c8]      = *(const short8*)Br0;
  *(short8*)&Bs[0][64 + rA][c8] = *(const short8*)Br1;
  short8 pa0 = *(const short8*)(Ar0 + 32);
  short8 pb0 = *(const short8*)(Br0 + 32);
  short8 pb1 = *(const short8*)(Br1 + 32);
  __syncthreads();
  for (int t = 0; t < 16; ++t) {
    const int cur = t & 1;
    short8 af[2], bfr[4];
    #pragma unroll
    for (int mf = 0; mf < 2; ++mf)
      af[mf] = *(const short8*)&As[cur][wr*32 + mf*16 + (lane & 15)][(lane >> 4)*8];
    #pragma unroll
    for (int nf = 0; nf < 4; ++nf)
      bfr[nf] = *(const short8*)&Bs[cur][wc*64 + nf*16 + (lane & 15)][(lane >> 4)*8];
    __builtin_amdgcn_s_setprio(1);
    #pragma unroll
    for (int mf = 0; mf < 2; ++mf)
      #pragma unroll
      for (int nf = 0; nf < 4; ++nf)
        acc[mf][nf] = __builtin_amdgcn_mfma_f32_16x16x32_bf16(af[mf], bfr[nf], acc[mf][nf], 0, 0, 0);
    __builtin_amdgcn_s_setprio(0);
    if (t < 15) {
      *(short8*)&As[cur^1][rA][c8]      = pa0;
      *(short8*)&Bs[cur^1][rA][c8]      = pb0;
      *(short8*)&Bs[cur^1][64 + rA][c8] = pb1;
      if (t < 14) {
        const int kc = (t + 2) * 32;
        pa0 = *(const short8*)(Ar0 + kc);
        pb0 = *(const short8*)(Br0 + kc);
        pb1 = *(const short8*)(Br1 + kc);
      }
      __syncthreads();
    }
  }
  const int mw = m0 + wr*32, cw = n0 + wc*64;
  if (ntile < 4) {              // ---- Q, rotary * qscale (exp2-domain)
    #pragma unroll
    for (int nfp = 0; nfp < 2; ++nfp) {
      const int c_lo = cw + nfp*16 + (lane & 15);
      const int head = c_lo >> 6, ii = c_lo & 31;
      const float* tb = tabs + ii;
      #pragma unroll
      for (int mf = 0; mf < 2; ++mf) {
        #pragma unroll
        for (int r = 0; r < 4; ++r) {
          int mm = mw + mf*16 + (lane >> 4)*4 + r;
          int bb = mm >> 11, n = mm & (NS-1);
          float cv = tb[n*32], sv = tb[TAB + n*32], qs = tb[2*TAB + n*32];
          float lo = acc[mf][nfp][r], hi = acc[mf][nfp+2][r];
          size_t base = (((size_t)bb*NH + head)*NS + n)*DH;
          q[base + ii]      = f2bf((lo*cv - hi*sv)*qs);
          q[base + ii + 32] = f2bf((hi*cv + lo*sv)*qs);
        }
      }
    }
  } else if (ntile == 4) {      // ---- K, rotary * (1/scale)
    #pragma unroll
    for (int nfp = 0; nfp < 2; ++nfp) {
      const int c_lo = cw + nfp*16 + (lane & 15);
      const int kvh = (c_lo - 512) >> 6, ii = c_lo & 31;
      const float* tb = tabs + ii;
      #pragma unroll
      for (int mf = 0; mf < 2; ++mf) {
        #pragma unroll
        for (int r = 0; r < 4; ++r) {
          int mm = mw + mf*16 + (lane >> 4)*4 + r;
          int bb = mm >> 11, n = mm & (NS-1);
          float cv = tb[n*32], sv = tb[TAB + n*32], ks = tb[3*TAB + n*32];
          float lo = acc[mf][nfp][r], hi = acc[mf][nfp+2][r];
          size_t base = (((size_t)bb*NKV + kvh)*NS + n)*DH;
          k[base + ii]      = f2bf((lo*cv - hi*sv)*ks);
          k[base + ii + 32] = f2bf((hi*cv + lo*sv)*ks);
        }
      }
    }
  } else {                      // ---- V: store transposed [b][kvh][d][n] (4-wide along n)
    #pragma unroll
    for (int nf = 0; nf < 4; ++nf) {
      const int c = cw + nf*16 + (lane & 15);
      const int rel = c - 640;
      const int kvh = rel >> 6, dd = rel & 63;
      #pragma unroll
      for (int mf = 0; mf < 2; ++mf) {
        int mm = mw + mf*16 + (lane >> 4)*4;
        int bb = mm >> 11, n = mm & (NS-1);
        s16x4 sv4;
        #pragma unroll
        for (int r = 0; r < 4; ++r) sv4[r] = (short)f2bf(acc[mf][nf][r]);
        *(s16x4*)&v[(((size_t)bb*NKV + kvh)*DH + dd)*NS + n] = sv4;
      }
    }
  }
}

// ---------- flash attention: 512 blocks, 4 waves x 32 q-rows, 32x32x16 swapped-QK^T,
// SOFTWARE-PIPELINED: QK^T(t) overlaps softmax(t-1)+PV(t-1); V-staging lags K by 1 tile
__global__ __launch_bounds__(256, 2) void attn_kernel(const unsigned short* __restrict__ q,
    const unsigned short* __restrict__ kg, const unsigned short* __restrict__ vtp,
    unsigned short* __restrict__ ao) {
  __shared__ __align__(16) short kt[2][64][72];
  __shared__ __align__(16) short vt[2][64][72];
  __shared__ float l_lds[4][32];
  const int bid = blockIdx.x;
  const int dsr = (bid & 7) * 64 + (bid >> 3);     // XCD-chunk swizzle (512 % 8 == 0)
  const int qt = dsr & 15, bh = dsr >> 4;
  const int h = bh & 7, b = bh >> 3;
  const int kvh = h & (NKV-1);                      // tile semantics: head h -> kv head h%2
  const int q0 = qt * 128;
  const int tid = threadIdx.x, w = tid >> 6, lane = tid & 63;
  const int l31 = lane & 31, hf = lane >> 5;
  short8 q8[4];
  const unsigned short* qp = q + (((size_t)b*NH + h)*NS + q0 + w*32 + l31)*DH + hf*8;
  #pragma unroll
  for (int s = 0; s < 4; ++s) q8[s] = *(const short8*)(qp + s*16);
  const unsigned short* kb = kg + ((size_t)b*NKV + kvh)*NS*DH;
  const unsigned short* vb = vtp + ((size_t)b*NKV + kvh)*DH*NS;
  const int srow = tid >> 2, scol = (tid & 3) * 16;
  // prologue: kt[0] <- K(0); regs: kreg = K(1), vreg = V(0)
  *(short8*)&kt[0][srow][scol]     = *(const short8*)&kb[(size_t)srow*DH + scol];
  *(short8*)&kt[0][srow][scol + 8] = *(const short8*)&kb[(size_t)srow*DH + scol + 8];
  short8 kr0 = *(const short8*)&kb[(size_t)(64 + srow)*DH + scol];
  short8 kr1 = *(const short8*)&kb[(size_t)(64 + srow)*DH + scol + 8];
  short8 vr0 = *(const short8*)&vb[(size_t)srow*NS + scol];
  short8 vr1 = *(const short8*)&vb[(size_t)srow*NS + scol + 8];
  f32x16 o0 = {}, o1 = {};
  f32x16 st0_o = {}, st1_o = {};
  float lsum = 0.f;
  __syncthreads();
  for (int t = 0; t < 32; ++t) {
    const int cur = t & 1;
    // ---- K-frags for tile t
    short8 kf0[4], kf1[4];
    #pragma unroll
    for (int s = 0; s < 4; ++s) {
      kf0[s] = *(const short8*)&kt[cur][l31][s*16 + hf*8];
      kf1[s] = *(const short8*)&kt[cur][32 + l31][s*16 + hf*8];
    }
    // ---- QK^T(t): two independent 4-chains; softmax(t-1) below is independent VALU
    //      work the scheduler interleaves into the MFMA latency
    f32x16 st0 = {}, st1 = {};
    #pragma unroll
    for (int s = 0; s < 4; ++s) {
      st0 = __builtin_amdgcn_mfma_f32_32x32x16_bf16(kf0[s], q8[s], st0, 0, 0, 0);
      st1 = __builtin_amdgcn_mfma_f32_32x32x16_bf16(kf1[s], q8[s], st1, 0, 0, 0);
    }
    if (t > 0) {
      // ---- softmax of tile t-1 (registers only)
      float p0[16], p1[16];
      #pragma unroll
      for (int r = 0; r < 16; ++r) {
        p0[r] = exp2_raw(st0_o[r]);
        p1[r] = exp2_raw(st1_o[r]);
        lsum += p0[r] + p1[r];
      }
      short8 paf[4];
      #pragma unroll
      for (int t2 = 0; t2 < 2; ++t2) {
        const float* pp = t2 ? p1 : p0;
        #pragma unroll
        for (int w16 = 0; w16 < 2; ++w16) {
          const int rb = w16*8;
          unsigned x = cvt_pk_bf16(pp[rb+0], pp[rb+1]);
          unsigned z = cvt_pk_bf16(pp[rb+2], pp[rb+3]);
          unsigned y = cvt_pk_bf16(pp[rb+4], pp[rb+5]);
          unsigned u = cvt_pk_bf16(pp[rb+6], pp[rb+7]);
          uint2v r1 = __builtin_amdgcn_permlane32_swap(x, y, false, false);
          uint2v r2 = __builtin_amdgcn_permlane32_swap(z, u, false, false);
          uint4v pk4;
          pk4[0] = r1[0]; pk4[1] = r2[0]; pk4[2] = r1[1]; pk4[3] = r2[1];
          paf[t2*2 + w16] = __builtin_bit_cast(short8, pk4);
        }
      }
      // ---- PV(t-1): V(t-1) lives in vt[cur^1]
      __builtin_amdgcn_s_setprio(1);
      #pragma unroll
      for (int kwin = 0; kwin < 4; ++kwin) {
        short8 vf0 = *(const short8*)&vt[cur^1][l31][kwin*16 + hf*8];
        short8 vf1 = *(const short8*)&vt[cur^1][32 + l31][kwin*16 + hf*8];
        o0 = __builtin_amdgcn_mfma_f32_32x32x16_bf16(paf[kwin], vf0, o0, 0, 0, 0);
        o1 = __builtin_amdgcn_mfma_f32_32x32x16_bf16(paf[kwin], vf1, o1, 0, 0, 0);
      }
      __builtin_amdgcn_s_setprio(0);
    }
    // ---- stage: kt[(t+1)&1] <- K(t+1), vt[t&1] <- V(t); prefetch K(t+2), V(t+1)
    if (t < 31) {
      *(short8*)&kt[cur^1][srow][scol]     = kr0;
      *(short8*)&kt[cur^1][srow][scol + 8] = kr1;
    }
    *(short8*)&vt[cur][srow][scol]     = vr0;
    *(short8*)&vt[cur][srow][scol + 8] = vr1;
    if (t < 30) {
      const int k2 = (t + 2) * 64;
      kr0 = *(const short8*)&kb[(size_t)(k2 + srow)*DH + scol];
      kr1 = *(const short8*)&kb[(size_t)(k2 + srow)*DH + scol + 8];
    }
    if (t < 31) {
      const int kv1 = (t + 1) * 64;
      vr0 = *(const short8*)&vb[(size_t)srow*NS + kv1 + scol];
      vr1 = *(const short8*)&vb[(size_t)srow*NS + kv1 + scol + 8];
    }
    __syncthreads();
    st0_o = st0; st1_o = st1;
  }
  // ---- epilogue: softmax + PV for tile 31 (V(31) in vt[1])
  {
    float p0[16], p1[16];
    #pragma unroll
    for (int r = 0; r < 16; ++r) {
      p0[r] = exp2_raw(st0_o[r]);
      p1[r] = exp2_raw(st1_o[r]);
      lsum += p0[r] + p1[r];
    }
    short8 paf[4];
    #pragma unroll
    for (int t2 = 0; t2 < 2; ++t2) {
      const float* pp = t2 ? p1 : p0;
      #pragma unroll
      for (int w16 = 0; w16 < 2; ++w16) {
        const int rb = w16*8;
        unsigned x = cvt_pk_bf16(pp[rb+0], pp[rb+1]);
        unsigned z = cvt_pk_bf16(pp[rb+2], pp[rb+3]);
        unsigned y = cvt_pk_bf16(pp[rb+4], pp[rb+5]);
        unsigned u = cvt_pk_bf16(pp[rb+6], pp[rb+7]);
        uint2v r1 = __builtin_amdgcn_permlane32_swap(x, y, false, false);
        uint2v r2 = __builtin_amdgcn_permlane32_swap(z, u, false, false);
        uint4v pk4;
        pk4[0] = r1[0]; pk4[1] = r2[0]; pk4[2] = r1[1]; pk4[3] = r2[1];
        paf[t2*2 + w16] = __builtin_bit_cast(short8, pk4);
      }
    }
    #pragma unroll
    for (int kwin = 0; kwin < 4; ++kwin) {
      short8 vf0 = *(const short8*)&vt[1][l31][kwin*16 + hf*8];
      short8 vf1 = *(const short8*)&vt[1][32 + l31][kwin*16 + hf*8];
      o0 = __builtin_amdgcn_mfma_f32_32x32x16_bf16(paf[kwin], vf0, o0, 0, 0, 0);
      o1 = __builtin_amdgcn_mfma_f32_32x32x16_bf16(paf[kwin], vf1, o1, 0, 0, 0);
    }
  }
  lsum += __shfl_xor(lsum, 32);
  if (hf == 0) {
    float rl;
    asm("v_rcp_f32 %0, %1" : "=v"(rl) : "v"(lsum));
    l_lds[w][l31] = rl;
  }
  asm volatile("s_waitcnt lgkmcnt(0)" ::: "memory");
  __builtin_amdgcn_sched_barrier(0);
  #pragma unroll
  for (int r = 0; r < 16; ++r) {
    const int ql = (r & 3) + 8*(r >> 2) + 4*hf;
    const float rl = l_lds[w][ql];
    const int n = q0 + w*32 + ql;
    unsigned short* aor = &ao[((size_t)b*NS + n)*DIM + h*DH + l31];
    aor[0]  = f2bf(o0[r] * rl);
    aor[32] = f2bf(o1[r] * rl);
  }
}

// ---------- out GEMM, 64x128 tile (wave 32x64), dbuf single-barrier: ao @ Woutt^T + xn + bout
__global__ __launch_bounds__(256, 3) void out_kernel(const unsigned short* __restrict__ A,
    const unsigned short* __restrict__ Bt, const unsigned short* __restrict__ xn,
    const float* __restrict__ bout, float* __restrict__ out) {
  __shared__ __align__(16) short As[2][64][40];
  __shared__ __align__(16) short Bs[2][128][40];
  const int m0 = blockIdx.x * 64, n0 = blockIdx.y * 128;
  const int tid = threadIdx.x, w = tid >> 6, lane = tid & 63;
  const int wr = w >> 1, wc = w & 1;
  f32x4 acc[2][4];
  #pragma unroll
  for (int i = 0; i < 2; ++i)
    #pragma unroll
    for (int j = 0; j < 4; ++j) acc[i][j] = (f32x4){0.f,0.f,0.f,0.f};
  const int rA = tid >> 2, c8 = (tid & 3) * 8;
  const unsigned short* Ar0 = &A[(size_t)(m0 + rA)*DIM + c8];
  const unsigned short* Br0 = &Bt[(size_t)(n0 + rA)*DIM + c8];
  const unsigned short* Br1 = &Bt[(size_t)(n0 + 64 + rA)*DIM + c8];
  *(short8*)&As[0][rA][c8]      = *(const short8*)Ar0;
  *(short8*)&Bs[0][rA][c8]      = *(const short8*)Br0;
  *(short8*)&Bs[0][64 + rA][c8] = *(const short8*)Br1;
  short8 pa0 = *(const short8*)(Ar0 + 32);
  short8 pb0 = *(const short8*)(Br0 + 32);
  short8 pb1 = *(const short8*)(Br1 + 32);
  __syncthreads();
  for (int t = 0; t < 16; ++t) {
    const int cur = t & 1;
    short8 af[2], bfr[4];
    #pragma unroll
    for (int mf = 0; mf < 2; ++mf)
      af[mf] = *(const short8*)&As[cur][wr*32 + mf*16 + (lane & 15)][(lane >> 4)*8];
    #pragma unroll
    for (int nf = 0; nf < 4; ++nf)
      bfr[nf] = *(const short8*)&Bs[cur][wc*64 + nf*16 + (lane & 15)][(lane >> 4)*8];
    __builtin_amdgcn_s_setprio(1);
    #pragma unroll
    for (int mf = 0; mf < 2; ++mf)
      #pragma unroll
      for (int nf = 0; nf < 4; ++nf)
        acc[mf][nf] = __builtin_amdgcn_mfma_f32_16x16x32_bf16(af[mf], bfr[nf], acc[mf][nf], 0, 0, 0);
    __builtin_amdgcn_s_setprio(0);
    if (t < 15) {
      *(short8*)&As[cur^1][rA][c8]      = pa0;
      *(short8*)&Bs[cur^1][rA][c8]      = pb0;
      *(short8*)&Bs[cur^1][64 + rA][c8] = pb1;
      if (t < 14) {
        const int kc = (t + 2) * 32;
        pa0 = *(const short8*)(Ar0 + kc);
        pb0 = *(const short8*)(Br0 + kc);
        pb1 = *(const short8*)(Br1 + kc);
      }
      __syncthreads();
    }
  }
  const int mw = m0 + wr*32, cw = n0 + wc*64;
  #pragma unroll
  for (int nf = 0; nf < 4; ++nf) {
    const int d = cw + nf*16 + (lane & 15);
    const float bo = bout[d];
    #pragma unroll
    for (int mf = 0; mf < 2; ++mf) {
      const int mb = mw + mf*16 + (lane >> 4)*4;
      const int bb = mb >> 11, n = mb & (NS-1);
      f32x4 res;
      #pragma unroll
      for (int r = 0; r < 4; ++r)
        res[r] = acc[mf][nf][r] + bf2f(xn[(size_t)(mb + r)*DIM + d]) + bo;
      *(f32x4*)&out[((size_t)bb*DIM + d)*NS + n] = res;
    }
  }
}

extern "C" void kernel_launch(void* const* d_in, const int* in_sizes, int n_in,
                              void* d_out, int out_size, void* d_ws, size_t ws_size,
                              hipStream_t stream) {
  (void)in_sizes; (void)n_in; (void)out_size; (void)ws_size;
  const float* x     = (const float*)d_in[0];
  const float* gamma = (const float*)d_in[1];
  const float* beta  = (const float*)d_in[2];
  const float* Wq    = (const float*)d_in[3];
  const float* Wkv   = (const float*)d_in[4];
  const float* Wout  = (const float*)d_in[5];
  const float* bout  = (const float*)d_in[6];
  float* out = (float*)d_out;
  char* ws = (char*)d_ws;
  unsigned short* xn    = (unsigned short*)(ws);                         // 8 MB
  unsigned short* qb    = (unsigned short*)(ws + (size_t)(8<<20));       // 8 MB
  unsigned short* kb    = (unsigned short*)(ws + (size_t)(16<<20));      // 2 MB
  unsigned short* vb    = (unsigned short*)(ws + (size_t)(18<<20));      // 2 MB (V^T)
  unsigned short* ao    = (unsigned short*)(ws + (size_t)(20<<20));      // 8 MB
  unsigned short* wqkvt = (unsigned short*)(ws + (size_t)(28<<20));      // 768 KB
  unsigned short* woutt = (unsigned short*)(ws + (size_t)(28<<20) + 786432); // 512 KB
  float* tabs           = (float*)(ws + (size_t)(28<<20) + 786432 + 524288); // 1 MB

  ln_kernel<<<dim3(64, 4), dim3(256), 0, stream>>>(x, gamma, beta, xn);
  prep_kernel<<<dim3(168), dim3(256), 0, stream>>>(Wq, Wkv, Wout, wqkvt, woutt, tabs);
  qkv_kernel<<<dim3(128, 6), dim3(256), 0, stream>>>(xn, wqkvt, tabs, qb, kb, vb);
  attn_kernel<<<dim3(512), dim3(256), 0, stream>>>(qb, kb, vb, ao);
  out_kernel<<<dim3(128, 4), dim3(256), 0, stream>>>(ao, woutt, xn, bout, out);
}

// Round 10
// 89.477 us; speedup vs baseline: 1.0258x; 1.0258x over previous
//
#include <hip/hip_runtime.h>
#include <stdint.h>

#define DIM 512
#define DH  64
#define NH  8
#define NKV 2
#define NB  4
#define NS  2048
#define TAB (NS*32)

typedef __attribute__((ext_vector_type(8))) short short8;
typedef __attribute__((ext_vector_type(4))) short s16x4;
typedef __attribute__((ext_vector_type(4))) float f32x4;
typedef __attribute__((ext_vector_type(16))) float f32x16;
typedef __attribute__((ext_vector_type(2))) unsigned uint2v;
typedef __attribute__((ext_vector_type(4))) unsigned uint4v;

__device__ __forceinline__ unsigned short f2bf(float f) {
  union { float f; unsigned u; } v; v.f = f;
  return (unsigned short)((v.u + 0x7fffu + ((v.u >> 16) & 1u)) >> 16);
}
__device__ __forceinline__ float bf2f(unsigned short b) {
  union { unsigned u; float f; } v; v.u = ((unsigned)b) << 16;
  return v.f;
}
__device__ __forceinline__ unsigned cvt_pk_bf16(float a, float b) {
  unsigned r;
  asm("v_cvt_pk_bf16_f32 %0, %1, %2" : "=v"(r) : "v"(a), "v"(b));
  return r;
}
__device__ __forceinline__ float exp2_raw(float x) {
  float r;
  asm("v_exp_f32 %0, %1" : "=v"(r) : "v"(x));
  return r;
}
__device__ __forceinline__ float rcp_raw(float x) {
  float r;
  asm("v_rcp_f32 %0, %1" : "=v"(r) : "v"(x));
  return r;
}
// merge two bf16x8 partials with scale rl -> bf16x8
__device__ __forceinline__ short8 merge8(short8 a, short8 b, float rl) {
  uint4v u;
  #pragma unroll
  for (int i = 0; i < 4; ++i) {
    float x0 = (bf2f((unsigned short)a[2*i])   + bf2f((unsigned short)b[2*i]))   * rl;
    float x1 = (bf2f((unsigned short)a[2*i+1]) + bf2f((unsigned short)b[2*i+1])) * rl;
    u[i] = cvt_pk_bf16(x0, x1);
  }
  return __builtin_bit_cast(short8, u);
}

// ---------- fused LayerNorm (blocks 0..255) + weight cvt (256..415) + tables (416..423)
__global__ __launch_bounds__(256) void lnprep_kernel(const float* __restrict__ x,
    const float* __restrict__ gamma, const float* __restrict__ beta,
    const float* __restrict__ Wq, const float* __restrict__ Wkv, const float* __restrict__ Wout,
    unsigned short* __restrict__ xn, unsigned short* __restrict__ Wqkvt,
    unsigned short* __restrict__ Woutt, float* __restrict__ tabs) {
  __shared__ float t[64][65];
  const int gid = blockIdx.x;
  const int tid = threadIdx.x;
  if (gid < 256) {                // ---- LayerNorm, one pass
    const int b = gid >> 6;
    const int n0 = (gid & 63) * 32;
    const int nl = tid & 31, grp = tid >> 5;
    const float* xb = x + (size_t)b * DIM * NS + (size_t)grp * 64 * NS + n0 + nl;
    float v[64];
    float s = 0.f, s2 = 0.f;
    #pragma unroll
    for (int i = 0; i < 64; ++i) {
      v[i] = xb[(size_t)i * NS];
      s += v[i]; s2 += v[i] * v[i];
    }
    float* sm = &t[0][0];          // [8][32]
    float* sq = &t[8][0];          // reuse prep LDS
    float* mu_s = &t[16][0];
    float* rs_s = &t[17][0];
    sm[grp*32 + nl] = s; sq[grp*32 + nl] = s2;
    __syncthreads();
    if (tid < 32) {
      float ts = 0.f, ts2 = 0.f;
      #pragma unroll
      for (int g = 0; g < 8; ++g) { ts += sm[g*32 + tid]; ts2 += sq[g*32 + tid]; }
      float mu = ts * (1.f/512.f);
      float var = ts2 * (1.f/512.f) - mu*mu;
      mu_s[tid] = mu; rs_s[tid] = rsqrtf(var + 1e-5f);
    }
    __syncthreads();
    const float mu = mu_s[nl], rs = rs_s[nl];
    unsigned short* dst = &xn[((size_t)(b*NS + n0 + nl))*DIM + grp*64];
    #pragma unroll
    for (int c = 0; c < 8; ++c) {
      short8 o;
      #pragma unroll
      for (int j = 0; j < 8; ++j) {
        int d = grp*64 + c*8 + j;
        o[j] = (short)f2bf((v[c*8 + j] - mu) * rs * gamma[d] + beta[d]);
      }
      *(short8*)&dst[c*8] = o;
    }
    return;
  }
  const int id = gid - 256;
  if (id >= 160) {               // ---- rotary tables
    int base = (id - 160) * 256 + tid;
    #pragma unroll 4
    for (int ii = 0; ii < 32; ++ii) {
      int tix = base + ii * 2048;
      int pos = tix >> 5, i = tix & 31;
      float inv = exp2f(-(float)i * (13.287712379549449f / 32.f));  // 10000^(-2i/64)
      float ang = (float)pos * inv;
      float sv, cv; sincosf(ang, &sv, &cv);
      float bse = ((float)(2*i) + 25.6f) / 89.6f;
      float power = ((float)pos - 1024.f) / 4096.f;
      float sc = exp2f(power * log2f(bse));
      tabs[tix]         = cv;
      tabs[TAB + tix]   = sv;
      tabs[2*TAB + tix] = sc * 0.125f * 1.4426950408889634f;  // qscale*1/sqrt(dh)*log2e
      tabs[3*TAB + tix] = 1.f / sc;                           // k scale
    }
    return;
  }
  const float* src; int W, k0, c0; unsigned short* dst; int drow0;
  if (id < 64)      { src = Wq;  W = 512; k0 = (id>>3)*64;        c0 = (id&7)*64;        dst = Wqkvt; drow0 = c0; }
  else if (id < 96) { int i2 = id-64; src = Wkv; W = 256; k0 = (i2>>2)*64; c0 = (i2&3)*64; dst = Wqkvt; drow0 = 512 + c0; }
  else              { int i3 = id-96; src = Wout; W = 512; k0 = (i3>>3)*64; c0 = (i3&7)*64; dst = Woutt; drow0 = c0; }
  #pragma unroll 4
  for (int it = 0; it < 16; ++it) {
    int row = it*4 + (tid>>6), col = tid & 63;
    t[row][col] = src[(size_t)(k0+row)*W + c0 + col];
  }
  __syncthreads();
  #pragma unroll 4
  for (int it = 0; it < 16; ++it) {
    int row = it*4 + (tid>>6), col = tid & 63;
    dst[(size_t)(drow0 + row)*512 + k0 + col] = f2bf(t[col][row]);
  }
}

// ---------- QKV GEMM, 64x128 tile (wave 32x64), dbuf single-barrier; fused rotary; V^T store
__global__ __launch_bounds__(256, 3) void qkv_kernel(const unsigned short* __restrict__ A,
    const unsigned short* __restrict__ Bt, const float* __restrict__ tabs,
    unsigned short* __restrict__ q, unsigned short* __restrict__ k,
    unsigned short* __restrict__ v) {
  __shared__ __align__(16) short As[2][64][40];
  __shared__ __align__(16) short Bs[2][128][40];
  const int m0 = blockIdx.x * 64, ntile = blockIdx.y, n0 = ntile * 128;
  const int tid = threadIdx.x, w = tid >> 6, lane = tid & 63;
  const int wr = w >> 1, wc = w & 1;
  f32x4 acc[2][4];
  #pragma unroll
  for (int i = 0; i < 2; ++i)
    #pragma unroll
    for (int j = 0; j < 4; ++j) acc[i][j] = (f32x4){0.f,0.f,0.f,0.f};
  const int rA = tid >> 2, c8 = (tid & 3) * 8;
  const unsigned short* Ar0 = &A[(size_t)(m0 + rA)*DIM + c8];
  const unsigned short* Br0 = &Bt[(size_t)(n0 + rA)*DIM + c8];
  const unsigned short* Br1 = &Bt[(size_t)(n0 + 64 + rA)*DIM + c8];
  *(short8*)&As[0][rA][c8]      = *(const short8*)Ar0;
  *(short8*)&Bs[0][rA][c8]      = *(const short8*)Br0;
  *(short8*)&Bs[0][64 + rA][c8] = *(const short8*)Br1;
  short8 pa0 = *(const short8*)(Ar0 + 32);
  short8 pb0 = *(const short8*)(Br0 + 32);
  short8 pb1 = *(const short8*)(Br1 + 32);
  __syncthreads();
  for (int t = 0; t < 16; ++t) {
    const int cur = t & 1;
    short8 af[2], bfr[4];
    #pragma unroll
    for (int mf = 0; mf < 2; ++mf)
      af[mf] = *(const short8*)&As[cur][wr*32 + mf*16 + (lane & 15)][(lane >> 4)*8];
    #pragma unroll
    for (int nf = 0; nf < 4; ++nf)
      bfr[nf] = *(const short8*)&Bs[cur][wc*64 + nf*16 + (lane & 15)][(lane >> 4)*8];
    __builtin_amdgcn_s_setprio(1);
    #pragma unroll
    for (int mf = 0; mf < 2; ++mf)
      #pragma unroll
      for (int nf = 0; nf < 4; ++nf)
        acc[mf][nf] = __builtin_amdgcn_mfma_f32_16x16x32_bf16(af[mf], bfr[nf], acc[mf][nf], 0, 0, 0);
    __builtin_amdgcn_s_setprio(0);
    if (t < 15) {
      *(short8*)&As[cur^1][rA][c8]      = pa0;
      *(short8*)&Bs[cur^1][rA][c8]      = pb0;
      *(short8*)&Bs[cur^1][64 + rA][c8] = pb1;
      if (t < 14) {
        const int kc = (t + 2) * 32;
        pa0 = *(const short8*)(Ar0 + kc);
        pb0 = *(const short8*)(Br0 + kc);
        pb1 = *(const short8*)(Br1 + kc);
      }
      __syncthreads();
    }
  }
  const int mw = m0 + wr*32, cw = n0 + wc*64;
  if (ntile < 4) {              // ---- Q, rotary * qscale (exp2-domain)
    #pragma unroll
    for (int nfp = 0; nfp < 2; ++nfp) {
      const int c_lo = cw + nfp*16 + (lane & 15);
      const int head = c_lo >> 6, ii = c_lo & 31;
      const float* tb = tabs + ii;
      #pragma unroll
      for (int mf = 0; mf < 2; ++mf) {
        #pragma unroll
        for (int r = 0; r < 4; ++r) {
          int mm = mw + mf*16 + (lane >> 4)*4 + r;
          int bb = mm >> 11, n = mm & (NS-1);
          float cv = tb[n*32], sv = tb[TAB + n*32], qs = tb[2*TAB + n*32];
          float lo = acc[mf][nfp][r], hi = acc[mf][nfp+2][r];
          size_t base = (((size_t)bb*NH + head)*NS + n)*DH;
          q[base + ii]      = f2bf((lo*cv - hi*sv)*qs);
          q[base + ii + 32] = f2bf((hi*cv + lo*sv)*qs);
        }
      }
    }
  } else if (ntile == 4) {      // ---- K, rotary * (1/scale)
    #pragma unroll
    for (int nfp = 0; nfp < 2; ++nfp) {
      const int c_lo = cw + nfp*16 + (lane & 15);
      const int kvh = (c_lo - 512) >> 6, ii = c_lo & 31;
      const float* tb = tabs + ii;
      #pragma unroll
      for (int mf = 0; mf < 2; ++mf) {
        #pragma unroll
        for (int r = 0; r < 4; ++r) {
          int mm = mw + mf*16 + (lane >> 4)*4 + r;
          int bb = mm >> 11, n = mm & (NS-1);
          float cv = tb[n*32], sv = tb[TAB + n*32], ks = tb[3*TAB + n*32];
          float lo = acc[mf][nfp][r], hi = acc[mf][nfp+2][r];
          size_t base = (((size_t)bb*NKV + kvh)*NS + n)*DH;
          k[base + ii]      = f2bf((lo*cv - hi*sv)*ks);
          k[base + ii + 32] = f2bf((hi*cv + lo*sv)*ks);
        }
      }
    }
  } else {                      // ---- V: store transposed [b][kvh][d][n] (4-wide along n)
    #pragma unroll
    for (int nf = 0; nf < 4; ++nf) {
      const int c = cw + nf*16 + (lane & 15);
      const int rel = c - 640;
      const int kvh = rel >> 6, dd = rel & 63;
      #pragma unroll
      for (int mf = 0; mf < 2; ++mf) {
        int mm = mw + mf*16 + (lane >> 4)*4;
        int bb = mm >> 11, n = mm & (NS-1);
        s16x4 sv4;
        #pragma unroll
        for (int r = 0; r < 4; ++r) sv4[r] = (short)f2bf(acc[mf][nf][r]);
        *(s16x4*)&v[(((size_t)bb*NKV + kvh)*DH + dd)*NS + n] = sv4;
      }
    }
  }
}

// ---------- flash attention, split-K x2: 1024 blocks (4/CU), 4 waves x 32 q-rows x 16 tiles,
// 32x32x16 swapped-QK^T, in-register exp2 softmax, dbuf K/V^T, unnormalized bf16 partials
__global__ __launch_bounds__(256, 4) void attn_kernel(const unsigned short* __restrict__ q,
    const unsigned short* __restrict__ kg, const unsigned short* __restrict__ vtp,
    unsigned short* __restrict__ op0, unsigned short* __restrict__ op1,
    float* __restrict__ lp) {
  __shared__ __align__(16) short kt[2][64][72];
  __shared__ __align__(16) short vt[2][64][72];
  const int bid = blockIdx.x;
  const int dsr = (bid & 7) * 128 + (bid >> 3);    // XCD-chunk swizzle (1024 % 8 == 0)
  const int qt   = dsr & 15;
  const int half = (dsr >> 4) & 1;
  const int bh   = dsr >> 5;                       // 0..31
  const int h = bh & 7, b = bh >> 3;
  const int kvh = h & (NKV-1);                     // tile semantics: head h -> kv head h%2
  const int q0 = qt * 128;
  const int tid = threadIdx.x, w = tid >> 6, lane = tid & 63;
  const int l31 = lane & 31, hf = lane >> 5;
  short8 q8[4];
  const unsigned short* qp = q + (((size_t)b*NH + h)*NS + q0 + w*32 + l31)*DH + hf*8;
  #pragma unroll
  for (int s = 0; s < 4; ++s) q8[s] = *(const short8*)(qp + s*16);
  const unsigned short* kb = kg + ((size_t)b*NKV + kvh)*NS*DH;
  const unsigned short* vb = vtp + ((size_t)b*NKV + kvh)*DH*NS;
  const int kbase = half * 1024;
  const int srow = tid >> 2, scol = (tid & 3) * 16;
  *(short8*)&kt[0][srow][scol]     = *(const short8*)&kb[(size_t)(kbase + srow)*DH + scol];
  *(short8*)&kt[0][srow][scol + 8] = *(const short8*)&kb[(size_t)(kbase + srow)*DH + scol + 8];
  *(short8*)&vt[0][srow][scol]     = *(const short8*)&vb[(size_t)srow*NS + kbase + scol];
  *(short8*)&vt[0][srow][scol + 8] = *(const short8*)&vb[(size_t)srow*NS + kbase + scol + 8];
  short8 kr0 = *(const short8*)&kb[(size_t)(kbase + 64 + srow)*DH + scol];
  short8 kr1 = *(const short8*)&kb[(size_t)(kbase + 64 + srow)*DH + scol + 8];
  short8 vr0 = *(const short8*)&vb[(size_t)srow*NS + kbase + 64 + scol];
  short8 vr1 = *(const short8*)&vb[(size_t)srow*NS + kbase + 64 + scol + 8];
  f32x16 o0 = {}, o1 = {};
  float lsum = 0.f;
  __syncthreads();
  for (int t = 0; t < 16; ++t) {
    const int cur = t & 1;
    short8 kf0[4], kf1[4];
    #pragma unroll
    for (int s = 0; s < 4; ++s) {
      kf0[s] = *(const short8*)&kt[cur][l31][s*16 + hf*8];
      kf1[s] = *(const short8*)&kt[cur][32 + l31][s*16 + hf*8];
    }
    f32x16 st0 = {}, st1 = {};
    __builtin_amdgcn_s_setprio(1);
    #pragma unroll
    for (int s = 0; s < 4; ++s) {
      st0 = __builtin_amdgcn_mfma_f32_32x32x16_bf16(kf0[s], q8[s], st0, 0, 0, 0);
      st1 = __builtin_amdgcn_mfma_f32_32x32x16_bf16(kf1[s], q8[s], st1, 0, 0, 0);
    }
    __builtin_amdgcn_s_setprio(0);
    float p0[16], p1[16];
    #pragma unroll
    for (int r = 0; r < 16; ++r) {
      p0[r] = exp2_raw(st0[r]);
      p1[r] = exp2_raw(st1[r]);
      lsum += p0[r] + p1[r];
    }
    short8 paf[4];
    #pragma unroll
    for (int t2 = 0; t2 < 2; ++t2) {
      const float* pp = t2 ? p1 : p0;
      #pragma unroll
      for (int w16 = 0; w16 < 2; ++w16) {
        const int rb = w16*8;
        unsigned x = cvt_pk_bf16(pp[rb+0], pp[rb+1]);
        unsigned z = cvt_pk_bf16(pp[rb+2], pp[rb+3]);
        unsigned y = cvt_pk_bf16(pp[rb+4], pp[rb+5]);
        unsigned u = cvt_pk_bf16(pp[rb+6], pp[rb+7]);
        uint2v r1 = __builtin_amdgcn_permlane32_swap(x, y, false, false);
        uint2v r2 = __builtin_amdgcn_permlane32_swap(z, u, false, false);
        uint4v pk4;
        pk4[0] = r1[0]; pk4[1] = r2[0]; pk4[2] = r1[1]; pk4[3] = r2[1];
        paf[t2*2 + w16] = __builtin_bit_cast(short8, pk4);
      }
    }
    __builtin_amdgcn_s_setprio(1);
    #pragma unroll
    for (int kwin = 0; kwin < 4; ++kwin) {
      short8 vf0 = *(const short8*)&vt[cur][l31][kwin*16 + hf*8];
      short8 vf1 = *(const short8*)&vt[cur][32 + l31][kwin*16 + hf*8];
      o0 = __builtin_amdgcn_mfma_f32_32x32x16_bf16(paf[kwin], vf0, o0, 0, 0, 0);
      o1 = __builtin_amdgcn_mfma_f32_32x32x16_bf16(paf[kwin], vf1, o1, 0, 0, 0);
    }
    __builtin_amdgcn_s_setprio(0);
    if (t < 15) {
      *(short8*)&kt[cur^1][srow][scol]     = kr0;
      *(short8*)&kt[cur^1][srow][scol + 8] = kr1;
      *(short8*)&vt[cur^1][srow][scol]     = vr0;
      *(short8*)&vt[cur^1][srow][scol + 8] = vr1;
      if (t < 14) {
        const int k2 = kbase + (t + 2) * 64;
        kr0 = *(const short8*)&kb[(size_t)(k2 + srow)*DH + scol];
        kr1 = *(const short8*)&kb[(size_t)(k2 + srow)*DH + scol + 8];
        vr0 = *(const short8*)&vb[(size_t)srow*NS + k2 + scol];
        vr1 = *(const short8*)&vb[(size_t)srow*NS + k2 + scol + 8];
      }
      __syncthreads();
    }
  }
  // ---- epilogue: per-row denominator (unreduced across halves) + unnormalized partials
  lsum += __shfl_xor(lsum, 32);
  if (hf == 0)
    lp[(size_t)half*NB*NH*NS + ((size_t)b*NH + h)*NS + q0 + w*32 + l31] = lsum;
  unsigned short* op = half ? op1 : op0;
  #pragma unroll
  for (int r = 0; r < 16; ++r) {
    const int ql = (r & 3) + 8*(r >> 2) + 4*hf;
    const int n = q0 + w*32 + ql;
    unsigned short* aor = &op[((size_t)b*NS + n)*DIM + h*DH + l31];
    aor[0]  = f2bf(o0[r]);
    aor[32] = f2bf(o1[r]);
  }
}

// ---------- out GEMM with fused split-K merge: A = (op0+op1)*rcp(l0+l1) in staging;
// 64x128 tile, dbuf single-barrier; + xn residual + bout -> out (b,512,2048) f32
__global__ __launch_bounds__(256, 3) void out_kernel(const unsigned short* __restrict__ op0,
    const unsigned short* __restrict__ op1, const float* __restrict__ lp,
    const unsigned short* __restrict__ Bt, const unsigned short* __restrict__ xn,
    const float* __restrict__ bout, float* __restrict__ out) {
  __shared__ __align__(16) short As[2][64][40];
  __shared__ __align__(16) short Bs[2][128][40];
  const int m0 = blockIdx.x * 64, n0 = blockIdx.y * 128;
  const int tid = threadIdx.x, w = tid >> 6, lane = tid & 63;
  const int wr = w >> 1, wc = w & 1;
  f32x4 acc[2][4];
  #pragma unroll
  for (int i = 0; i < 2; ++i)
    #pragma unroll
    for (int j = 0; j < 4; ++j) acc[i][j] = (f32x4){0.f,0.f,0.f,0.f};
  const int rA = tid >> 2, c8 = (tid & 3) * 8;
  const int rowm = m0 + rA;                        // b*2048 + n
  const int b0 = rowm >> 11, nn0 = rowm & (NS-1);
  const float* lp0 = lp + ((size_t)b0*NH)*NS + nn0;            // + h*NS
  const float* lp1 = lp0 + (size_t)NB*NH*NS;
  const unsigned short* A0 = &op0[(size_t)rowm*DIM + c8];
  const unsigned short* A1 = &op1[(size_t)rowm*DIM + c8];
  const unsigned short* Br0 = &Bt[(size_t)(n0 + rA)*DIM + c8];
  const unsigned short* Br1 = &Bt[(size_t)(n0 + 64 + rA)*DIM + c8];
  float rlc = rcp_raw(lp0[0] + lp1[0]);            // h = 0 (steps 0,1)
  *(short8*)&As[0][rA][c8]      = merge8(*(const short8*)A0, *(const short8*)A1, rlc);
  *(short8*)&Bs[0][rA][c8]      = *(const short8*)Br0;
  *(short8*)&Bs[0][64 + rA][c8] = *(const short8*)Br1;
  short8 pa0 = *(const short8*)(A0 + 32);
  short8 pa1 = *(const short8*)(A1 + 32);
  float rlp = rlc;                                  // step 1 also h = 0
  short8 pb0 = *(const short8*)(Br0 + 32);
  short8 pb1 = *(const short8*)(Br1 + 32);
  __syncthreads();
  for (int t = 0; t < 16; ++t) {
    const int cur = t & 1;
    short8 af[2], bfr[4];
    #pragma unroll
    for (int mf = 0; mf < 2; ++mf)
      af[mf] = *(const short8*)&As[cur][wr*32 + mf*16 + (lane & 15)][(lane >> 4)*8];
    #pragma unroll
    for (int nf = 0; nf < 4; ++nf)
      bfr[nf] = *(const short8*)&Bs[cur][wc*64 + nf*16 + (lane & 15)][(lane >> 4)*8];
    __builtin_amdgcn_s_setprio(1);
    #pragma unroll
    for (int mf = 0; mf < 2; ++mf)
      #pragma unroll
      for (int nf = 0; nf < 4; ++nf)
        acc[mf][nf] = __builtin_amdgcn_mfma_f32_16x16x32_bf16(af[mf], bfr[nf], acc[mf][nf], 0, 0, 0);
    __builtin_amdgcn_s_setprio(0);
    if (t < 15) {
      *(short8*)&As[cur^1][rA][c8]      = merge8(pa0, pa1, rlp);
      *(short8*)&Bs[cur^1][rA][c8]      = pb0;
      *(short8*)&Bs[cur^1][64 + rA][c8] = pb1;
      if (t < 14) {
        const int kc = (t + 2) * 32;
        pa0 = *(const short8*)(A0 + kc);
        pa1 = *(const short8*)(A1 + kc);
        pb0 = *(const short8*)(Br0 + kc);
        pb1 = *(const short8*)(Br1 + kc);
        const int h2 = (t + 2) >> 1;
        rlp = rcp_raw(lp0[h2*NS] + lp1[h2*NS]);
      }
      __syncthreads();
    }
  }
  const int mw = m0 + wr*32, cw = n0 + wc*64;
  #pragma unroll
  for (int nf = 0; nf < 4; ++nf) {
    const int d = cw + nf*16 + (lane & 15);
    const float bo = bout[d];
    #pragma unroll
    for (int mf = 0; mf < 2; ++mf) {
      const int mb = mw + mf*16 + (lane >> 4)*4;
      const int bb = mb >> 11, n = mb & (NS-1);
      f32x4 res;
      #pragma unroll
      for (int r = 0; r < 4; ++r)
        res[r] = acc[mf][nf][r] + bf2f(xn[(size_t)(mb + r)*DIM + d]) + bo;
      *(f32x4*)&out[((size_t)bb*DIM + d)*NS + n] = res;
    }
  }
}

extern "C" void kernel_launch(void* const* d_in, const int* in_sizes, int n_in,
                              void* d_out, int out_size, void* d_ws, size_t ws_size,
                              hipStream_t stream) {
  (void)in_sizes; (void)n_in; (void)out_size; (void)ws_size;
  const float* x     = (const float*)d_in[0];
  const float* gamma = (const float*)d_in[1];
  const float* beta  = (const float*)d_in[2];
  const float* Wq    = (const float*)d_in[3];
  const float* Wkv   = (const float*)d_in[4];
  const float* Wout  = (const float*)d_in[5];
  const float* bout  = (const float*)d_in[6];
  float* out = (float*)d_out;
  char* ws = (char*)d_ws;
  unsigned short* xn    = (unsigned short*)(ws);                         // 8 MB
  unsigned short* qb    = (unsigned short*)(ws + (size_t)(8<<20));       // 8 MB
  unsigned short* kb    = (unsigned short*)(ws + (size_t)(16<<20));      // 2 MB
  unsigned short* vb    = (unsigned short*)(ws + (size_t)(18<<20));      // 2 MB (V^T)
  unsigned short* op0   = (unsigned short*)(ws + (size_t)(20<<20));      // 8 MB (half-0 partial)
  unsigned short* op1   = (unsigned short*)(ws + (size_t)(28<<20));      // 8 MB (half-1 partial)
  unsigned short* wqkvt = (unsigned short*)(ws + (size_t)(36<<20));      // 768 KB
  unsigned short* woutt = (unsigned short*)(ws + (size_t)(36<<20) + 786432);           // 512 KB
  float* tabs           = (float*)(ws + (size_t)(36<<20) + 786432 + 524288);           // 1 MB
  float* lp             = (float*)(ws + (size_t)(36<<20) + 786432 + 524288 + 1048576); // 512 KB

  lnprep_kernel<<<dim3(424), dim3(256), 0, stream>>>(x, gamma, beta, Wq, Wkv, Wout,
                                                     xn, wqkvt, woutt, tabs);
  qkv_kernel<<<dim3(128, 6), dim3(256), 0, stream>>>(xn, wqkvt, tabs, qb, kb, vb);
  attn_kernel<<<dim3(1024), dim3(256), 0, stream>>>(qb, kb, vb, op0, op1, lp);
  out_kernel<<<dim3(128, 4), dim3(256), 0, stream>>>(op0, op1, lp, woutt, xn, bout, out);
}

// Round 11
// 85.336 us; speedup vs baseline: 1.0756x; 1.0485x over previous
//
#include <hip/hip_runtime.h>
#include <stdint.h>

#define DIM 512
#define DH  64
#define NH  8
#define NKV 2
#define NB  4
#define NS  2048
#define TAB (NS*32)

typedef __attribute__((ext_vector_type(8))) short short8;
typedef __attribute__((ext_vector_type(4))) short s16x4;
typedef __attribute__((ext_vector_type(4))) float f32x4;
typedef __attribute__((ext_vector_type(16))) float f32x16;
typedef __attribute__((ext_vector_type(2))) unsigned uint2v;
typedef __attribute__((ext_vector_type(4))) unsigned uint4v;

__device__ __forceinline__ unsigned short f2bf(float f) {
  union { float f; unsigned u; } v; v.f = f;
  return (unsigned short)((v.u + 0x7fffu + ((v.u >> 16) & 1u)) >> 16);
}
__device__ __forceinline__ float bf2f(unsigned short b) {
  union { unsigned u; float f; } v; v.u = ((unsigned)b) << 16;
  return v.f;
}
__device__ __forceinline__ unsigned cvt_pk_bf16(float a, float b) {
  unsigned r;
  asm("v_cvt_pk_bf16_f32 %0, %1, %2" : "=v"(r) : "v"(a), "v"(b));
  return r;
}
__device__ __forceinline__ float exp2_raw(float x) {
  float r;
  asm("v_exp_f32 %0, %1" : "=v"(r) : "v"(x));
  return r;
}
__device__ __forceinline__ float rcp_raw(float x) {
  float r;
  asm("v_rcp_f32 %0, %1" : "=v"(r) : "v"(x));
  return r;
}
// merge two bf16x8 partials with scale rl -> bf16x8
__device__ __forceinline__ short8 merge8(short8 a, short8 b, float rl) {
  uint4v u;
  #pragma unroll
  for (int i = 0; i < 4; ++i) {
    float x0 = (bf2f((unsigned short)a[2*i])   + bf2f((unsigned short)b[2*i]))   * rl;
    float x1 = (bf2f((unsigned short)a[2*i+1]) + bf2f((unsigned short)b[2*i+1])) * rl;
    u[i] = cvt_pk_bf16(x0, x1);
  }
  return __builtin_bit_cast(short8, u);
}

// ---------- fused LayerNorm (blocks 0..255) + weight cvt (256..415) + tables (416..423)
__global__ __launch_bounds__(256) void lnprep_kernel(const float* __restrict__ x,
    const float* __restrict__ gamma, const float* __restrict__ beta,
    const float* __restrict__ Wq, const float* __restrict__ Wkv, const float* __restrict__ Wout,
    unsigned short* __restrict__ xn, unsigned short* __restrict__ Wqkvt,
    unsigned short* __restrict__ Woutt, float* __restrict__ tabs) {
  __shared__ float t[64][65];
  const int gid = blockIdx.x;
  const int tid = threadIdx.x;
  if (gid < 256) {                // ---- LayerNorm, one pass
    const int b = gid >> 6;
    const int n0 = (gid & 63) * 32;
    const int nl = tid & 31, grp = tid >> 5;
    const float* xb = x + (size_t)b * DIM * NS + (size_t)grp * 64 * NS + n0 + nl;
    float v[64];
    float s = 0.f, s2 = 0.f;
    #pragma unroll
    for (int i = 0; i < 64; ++i) {
      v[i] = xb[(size_t)i * NS];
      s += v[i]; s2 += v[i] * v[i];
    }
    float* sm = &t[0][0];          // [8][32]
    float* sq = &t[8][0];          // reuse prep LDS
    float* mu_s = &t[16][0];
    float* rs_s = &t[17][0];
    sm[grp*32 + nl] = s; sq[grp*32 + nl] = s2;
    __syncthreads();
    if (tid < 32) {
      float ts = 0.f, ts2 = 0.f;
      #pragma unroll
      for (int g = 0; g < 8; ++g) { ts += sm[g*32 + tid]; ts2 += sq[g*32 + tid]; }
      float mu = ts * (1.f/512.f);
      float var = ts2 * (1.f/512.f) - mu*mu;
      mu_s[tid] = mu; rs_s[tid] = rsqrtf(var + 1e-5f);
    }
    __syncthreads();
    const float mu = mu_s[nl], rs = rs_s[nl];
    unsigned short* dst = &xn[((size_t)(b*NS + n0 + nl))*DIM + grp*64];
    #pragma unroll
    for (int c = 0; c < 8; ++c) {
      short8 o;
      #pragma unroll
      for (int j = 0; j < 8; ++j) {
        int d = grp*64 + c*8 + j;
        o[j] = (short)f2bf((v[c*8 + j] - mu) * rs * gamma[d] + beta[d]);
      }
      *(short8*)&dst[c*8] = o;
    }
    return;
  }
  const int id = gid - 256;
  if (id >= 160) {               // ---- rotary tables
    int base = (id - 160) * 256 + tid;
    #pragma unroll 4
    for (int ii = 0; ii < 32; ++ii) {
      int tix = base + ii * 2048;
      int pos = tix >> 5, i = tix & 31;
      float inv = exp2f(-(float)i * (13.287712379549449f / 32.f));  // 10000^(-2i/64)
      float ang = (float)pos * inv;
      float sv, cv; sincosf(ang, &sv, &cv);
      float bse = ((float)(2*i) + 25.6f) / 89.6f;
      float power = ((float)pos - 1024.f) / 4096.f;
      float sc = exp2f(power * log2f(bse));
      tabs[tix]         = cv;
      tabs[TAB + tix]   = sv;
      tabs[2*TAB + tix] = sc * 0.125f * 1.4426950408889634f;  // qscale*1/sqrt(dh)*log2e
      tabs[3*TAB + tix] = 1.f / sc;                           // k scale
    }
    return;
  }
  const float* src; int W, k0, c0; unsigned short* dst; int drow0;
  if (id < 64)      { src = Wq;  W = 512; k0 = (id>>3)*64;        c0 = (id&7)*64;        dst = Wqkvt; drow0 = c0; }
  else if (id < 96) { int i2 = id-64; src = Wkv; W = 256; k0 = (i2>>2)*64; c0 = (i2&3)*64; dst = Wqkvt; drow0 = 512 + c0; }
  else              { int i3 = id-96; src = Wout; W = 512; k0 = (i3>>3)*64; c0 = (i3&7)*64; dst = Woutt; drow0 = c0; }
  #pragma unroll 4
  for (int it = 0; it < 16; ++it) {
    int row = it*4 + (tid>>6), col = tid & 63;
    t[row][col] = src[(size_t)(k0+row)*W + c0 + col];
  }
  __syncthreads();
  #pragma unroll 4
  for (int it = 0; it < 16; ++it) {
    int row = it*4 + (tid>>6), col = tid & 63;
    dst[(size_t)(drow0 + row)*512 + k0 + col] = f2bf(t[col][row]);
  }
}

// ---------- QKV GEMM, 64x128 tile (wave 32x64), dbuf single-barrier; fused rotary; V^T store
__global__ __launch_bounds__(256, 3) void qkv_kernel(const unsigned short* __restrict__ A,
    const unsigned short* __restrict__ Bt, const float* __restrict__ tabs,
    unsigned short* __restrict__ q, unsigned short* __restrict__ k,
    unsigned short* __restrict__ v) {
  __shared__ __align__(16) short As[2][64][40];
  __shared__ __align__(16) short Bs[2][128][40];
  const int m0 = blockIdx.x * 64, ntile = blockIdx.y, n0 = ntile * 128;
  const int tid = threadIdx.x, w = tid >> 6, lane = tid & 63;
  const int wr = w >> 1, wc = w & 1;
  f32x4 acc[2][4];
  #pragma unroll
  for (int i = 0; i < 2; ++i)
    #pragma unroll
    for (int j = 0; j < 4; ++j) acc[i][j] = (f32x4){0.f,0.f,0.f,0.f};
  const int rA = tid >> 2, c8 = (tid & 3) * 8;
  const unsigned short* Ar0 = &A[(size_t)(m0 + rA)*DIM + c8];
  const unsigned short* Br0 = &Bt[(size_t)(n0 + rA)*DIM + c8];
  const unsigned short* Br1 = &Bt[(size_t)(n0 + 64 + rA)*DIM + c8];
  *(short8*)&As[0][rA][c8]      = *(const short8*)Ar0;
  *(short8*)&Bs[0][rA][c8]      = *(const short8*)Br0;
  *(short8*)&Bs[0][64 + rA][c8] = *(const short8*)Br1;
  short8 pa0 = *(const short8*)(Ar0 + 32);
  short8 pb0 = *(const short8*)(Br0 + 32);
  short8 pb1 = *(const short8*)(Br1 + 32);
  __syncthreads();
  for (int t = 0; t < 16; ++t) {
    const int cur = t & 1;
    short8 af[2], bfr[4];
    #pragma unroll
    for (int mf = 0; mf < 2; ++mf)
      af[mf] = *(const short8*)&As[cur][wr*32 + mf*16 + (lane & 15)][(lane >> 4)*8];
    #pragma unroll
    for (int nf = 0; nf < 4; ++nf)
      bfr[nf] = *(const short8*)&Bs[cur][wc*64 + nf*16 + (lane & 15)][(lane >> 4)*8];
    __builtin_amdgcn_s_setprio(1);
    #pragma unroll
    for (int mf = 0; mf < 2; ++mf)
      #pragma unroll
      for (int nf = 0; nf < 4; ++nf)
        acc[mf][nf] = __builtin_amdgcn_mfma_f32_16x16x32_bf16(af[mf], bfr[nf], acc[mf][nf], 0, 0, 0);
    __builtin_amdgcn_s_setprio(0);
    if (t < 15) {
      *(short8*)&As[cur^1][rA][c8]      = pa0;
      *(short8*)&Bs[cur^1][rA][c8]      = pb0;
      *(short8*)&Bs[cur^1][64 + rA][c8] = pb1;
      if (t < 14) {
        const int kc = (t + 2) * 32;
        pa0 = *(const short8*)(Ar0 + kc);
        pb0 = *(const short8*)(Br0 + kc);
        pb1 = *(const short8*)(Br1 + kc);
      }
      __syncthreads();
    }
  }
  const int mw = m0 + wr*32, cw = n0 + wc*64;
  if (ntile < 4) {              // ---- Q, rotary * qscale (exp2-domain)
    #pragma unroll
    for (int nfp = 0; nfp < 2; ++nfp) {
      const int c_lo = cw + nfp*16 + (lane & 15);
      const int head = c_lo >> 6, ii = c_lo & 31;
      const float* tb = tabs + ii;
      #pragma unroll
      for (int mf = 0; mf < 2; ++mf) {
        #pragma unroll
        for (int r = 0; r < 4; ++r) {
          int mm = mw + mf*16 + (lane >> 4)*4 + r;
          int bb = mm >> 11, n = mm & (NS-1);
          float cv = tb[n*32], sv = tb[TAB + n*32], qs = tb[2*TAB + n*32];
          float lo = acc[mf][nfp][r], hi = acc[mf][nfp+2][r];
          size_t base = (((size_t)bb*NH + head)*NS + n)*DH;
          q[base + ii]      = f2bf((lo*cv - hi*sv)*qs);
          q[base + ii + 32] = f2bf((hi*cv + lo*sv)*qs);
        }
      }
    }
  } else if (ntile == 4) {      // ---- K, rotary * (1/scale)
    #pragma unroll
    for (int nfp = 0; nfp < 2; ++nfp) {
      const int c_lo = cw + nfp*16 + (lane & 15);
      const int kvh = (c_lo - 512) >> 6, ii = c_lo & 31;
      const float* tb = tabs + ii;
      #pragma unroll
      for (int mf = 0; mf < 2; ++mf) {
        #pragma unroll
        for (int r = 0; r < 4; ++r) {
          int mm = mw + mf*16 + (lane >> 4)*4 + r;
          int bb = mm >> 11, n = mm & (NS-1);
          float cv = tb[n*32], sv = tb[TAB + n*32], ks = tb[3*TAB + n*32];
          float lo = acc[mf][nfp][r], hi = acc[mf][nfp+2][r];
          size_t base = (((size_t)bb*NKV + kvh)*NS + n)*DH;
          k[base + ii]      = f2bf((lo*cv - hi*sv)*ks);
          k[base + ii + 32] = f2bf((hi*cv + lo*sv)*ks);
        }
      }
    }
  } else {                      // ---- V: store transposed [b][kvh][d][n] (4-wide along n)
    #pragma unroll
    for (int nf = 0; nf < 4; ++nf) {
      const int c = cw + nf*16 + (lane & 15);
      const int rel = c - 640;
      const int kvh = rel >> 6, dd = rel & 63;
      #pragma unroll
      for (int mf = 0; mf < 2; ++mf) {
        int mm = mw + mf*16 + (lane >> 4)*4;
        int bb = mm >> 11, n = mm & (NS-1);
        s16x4 sv4;
        #pragma unroll
        for (int r = 0; r < 4; ++r) sv4[r] = (short)f2bf(acc[mf][nf][r]);
        *(s16x4*)&v[(((size_t)bb*NKV + kvh)*DH + dd)*NS + n] = sv4;
      }
    }
  }
}

// ---------- flash attention, split-K x2: 512 blocks x 512 threads (8 waves, 256 q-rows),
// 32 waves/CU resident; 32x32x16 swapped-QK^T, in-register exp2 softmax, dbuf K/V^T
__global__ __launch_bounds__(512, 2) void attn_kernel(const unsigned short* __restrict__ q,
    const unsigned short* __restrict__ kg, const unsigned short* __restrict__ vtp,
    unsigned short* __restrict__ op0, unsigned short* __restrict__ op1,
    float* __restrict__ lp) {
  __shared__ __align__(16) short kt[2][64][72];
  __shared__ __align__(16) short vt[2][64][72];
  const int bid = blockIdx.x;
  const int dsr = (bid & 7) * 64 + (bid >> 3);     // XCD-chunk swizzle (512 % 8 == 0)
  const int qt   = dsr & 7;                         // 8 q-tiles of 256 rows
  const int half = (dsr >> 3) & 1;
  const int bh   = dsr >> 4;                        // 0..31
  const int h = bh & 7, b = bh >> 3;
  const int kvh = h & (NKV-1);                      // tile semantics: head h -> kv head h%2
  const int q0 = qt * 256;
  const int tid = threadIdx.x, w = tid >> 6, lane = tid & 63;
  const int l31 = lane & 31, hf = lane >> 5;
  short8 q8[4];
  const unsigned short* qp = q + (((size_t)b*NH + h)*NS + q0 + w*32 + l31)*DH + hf*8;
  #pragma unroll
  for (int s = 0; s < 4; ++s) q8[s] = *(const short8*)(qp + s*16);
  const unsigned short* kb = kg + ((size_t)b*NKV + kvh)*NS*DH;
  const unsigned short* vb = vtp + ((size_t)b*NKV + kvh)*DH*NS;
  const int kbase = half * 1024;
  const int srow = tid >> 3, scol = (tid & 7) * 8;   // 512 threads: one short8 each
  *(short8*)&kt[0][srow][scol] = *(const short8*)&kb[(size_t)(kbase + srow)*DH + scol];
  *(short8*)&vt[0][srow][scol] = *(const short8*)&vb[(size_t)srow*NS + kbase + scol];
  short8 kr = *(const short8*)&kb[(size_t)(kbase + 64 + srow)*DH + scol];
  short8 vr = *(const short8*)&vb[(size_t)srow*NS + kbase + 64 + scol];
  f32x16 o0 = {}, o1 = {};
  float lsum = 0.f;
  __syncthreads();
  for (int t = 0; t < 16; ++t) {
    const int cur = t & 1;
    short8 kf0[4], kf1[4];
    #pragma unroll
    for (int s = 0; s < 4; ++s) {
      kf0[s] = *(const short8*)&kt[cur][l31][s*16 + hf*8];
      kf1[s] = *(const short8*)&kt[cur][32 + l31][s*16 + hf*8];
    }
    f32x16 st0 = {}, st1 = {};
    __builtin_amdgcn_s_setprio(1);
    #pragma unroll
    for (int s = 0; s < 4; ++s) {
      st0 = __builtin_amdgcn_mfma_f32_32x32x16_bf16(kf0[s], q8[s], st0, 0, 0, 0);
      st1 = __builtin_amdgcn_mfma_f32_32x32x16_bf16(kf1[s], q8[s], st1, 0, 0, 0);
    }
    __builtin_amdgcn_s_setprio(0);
    float p0[16], p1[16];
    #pragma unroll
    for (int r = 0; r < 16; ++r) {
      p0[r] = exp2_raw(st0[r]);
      p1[r] = exp2_raw(st1[r]);
      lsum += p0[r] + p1[r];
    }
    short8 paf[4];
    #pragma unroll
    for (int t2 = 0; t2 < 2; ++t2) {
      const float* pp = t2 ? p1 : p0;
      #pragma unroll
      for (int w16 = 0; w16 < 2; ++w16) {
        const int rb = w16*8;
        unsigned x = cvt_pk_bf16(pp[rb+0], pp[rb+1]);
        unsigned z = cvt_pk_bf16(pp[rb+2], pp[rb+3]);
        unsigned y = cvt_pk_bf16(pp[rb+4], pp[rb+5]);
        unsigned u = cvt_pk_bf16(pp[rb+6], pp[rb+7]);
        uint2v r1 = __builtin_amdgcn_permlane32_swap(x, y, false, false);
        uint2v r2 = __builtin_amdgcn_permlane32_swap(z, u, false, false);
        uint4v pk4;
        pk4[0] = r1[0]; pk4[1] = r2[0]; pk4[2] = r1[1]; pk4[3] = r2[1];
        paf[t2*2 + w16] = __builtin_bit_cast(short8, pk4);
      }
    }
    __builtin_amdgcn_s_setprio(1);
    #pragma unroll
    for (int kwin = 0; kwin < 4; ++kwin) {
      short8 vf0 = *(const short8*)&vt[cur][l31][kwin*16 + hf*8];
      short8 vf1 = *(const short8*)&vt[cur][32 + l31][kwin*16 + hf*8];
      o0 = __builtin_amdgcn_mfma_f32_32x32x16_bf16(paf[kwin], vf0, o0, 0, 0, 0);
      o1 = __builtin_amdgcn_mfma_f32_32x32x16_bf16(paf[kwin], vf1, o1, 0, 0, 0);
    }
    __builtin_amdgcn_s_setprio(0);
    if (t < 15) {
      *(short8*)&kt[cur^1][srow][scol] = kr;
      *(short8*)&vt[cur^1][srow][scol] = vr;
      if (t < 14) {
        const int k2 = kbase + (t + 2) * 64;
        kr = *(const short8*)&kb[(size_t)(k2 + srow)*DH + scol];
        vr = *(const short8*)&vb[(size_t)srow*NS + k2 + scol];
      }
      __syncthreads();
    }
  }
  // ---- epilogue: per-row denominator (per-half) + unnormalized bf16 partials
  lsum += __shfl_xor(lsum, 32);
  if (hf == 0)
    lp[(size_t)half*NB*NH*NS + ((size_t)b*NH + h)*NS + q0 + w*32 + l31] = lsum;
  unsigned short* op = half ? op1 : op0;
  #pragma unroll
  for (int r = 0; r < 16; ++r) {
    const int ql = (r & 3) + 8*(r >> 2) + 4*hf;
    const int n = q0 + w*32 + ql;
    unsigned short* aor = &op[((size_t)b*NS + n)*DIM + h*DH + l31];
    aor[0]  = f2bf(o0[r]);
    aor[32] = f2bf(o1[r]);
  }
}

// ---------- out GEMM with fused split-K merge: A = (op0+op1)*rcp(l0+l1) in staging;
// 64x128 tile, dbuf single-barrier; + xn residual + bout -> out (b,512,2048) f32
__global__ __launch_bounds__(256, 3) void out_kernel(const unsigned short* __restrict__ op0,
    const unsigned short* __restrict__ op1, const float* __restrict__ lp,
    const unsigned short* __restrict__ Bt, const unsigned short* __restrict__ xn,
    const float* __restrict__ bout, float* __restrict__ out) {
  __shared__ __align__(16) short As[2][64][40];
  __shared__ __align__(16) short Bs[2][128][40];
  const int m0 = blockIdx.x * 64, n0 = blockIdx.y * 128;
  const int tid = threadIdx.x, w = tid >> 6, lane = tid & 63;
  const int wr = w >> 1, wc = w & 1;
  f32x4 acc[2][4];
  #pragma unroll
  for (int i = 0; i < 2; ++i)
    #pragma unroll
    for (int j = 0; j < 4; ++j) acc[i][j] = (f32x4){0.f,0.f,0.f,0.f};
  const int rA = tid >> 2, c8 = (tid & 3) * 8;
  const int rowm = m0 + rA;                        // b*2048 + n
  const int b0 = rowm >> 11, nn0 = rowm & (NS-1);
  const float* lp0 = lp + ((size_t)b0*NH)*NS + nn0;            // + h*NS
  const float* lp1 = lp0 + (size_t)NB*NH*NS;
  const unsigned short* A0 = &op0[(size_t)rowm*DIM + c8];
  const unsigned short* A1 = &op1[(size_t)rowm*DIM + c8];
  const unsigned short* Br0 = &Bt[(size_t)(n0 + rA)*DIM + c8];
  const unsigned short* Br1 = &Bt[(size_t)(n0 + 64 + rA)*DIM + c8];
  float rlc = rcp_raw(lp0[0] + lp1[0]);            // h = 0 (steps 0,1)
  *(short8*)&As[0][rA][c8]      = merge8(*(const short8*)A0, *(const short8*)A1, rlc);
  *(short8*)&Bs[0][rA][c8]      = *(const short8*)Br0;
  *(short8*)&Bs[0][64 + rA][c8] = *(const short8*)Br1;
  short8 pa0 = *(const short8*)(A0 + 32);
  short8 pa1 = *(const short8*)(A1 + 32);
  float rlp = rlc;                                  // step 1 also h = 0
  short8 pb0 = *(const short8*)(Br0 + 32);
  short8 pb1 = *(const short8*)(Br1 + 32);
  __syncthreads();
  for (int t = 0; t < 16; ++t) {
    const int cur = t & 1;
    short8 af[2], bfr[4];
    #pragma unroll
    for (int mf = 0; mf < 2; ++mf)
      af[mf] = *(const short8*)&As[cur][wr*32 + mf*16 + (lane & 15)][(lane >> 4)*8];
    #pragma unroll
    for (int nf = 0; nf < 4; ++nf)
      bfr[nf] = *(const short8*)&Bs[cur][wc*64 + nf*16 + (lane & 15)][(lane >> 4)*8];
    __builtin_amdgcn_s_setprio(1);
    #pragma unroll
    for (int mf = 0; mf < 2; ++mf)
      #pragma unroll
      for (int nf = 0; nf < 4; ++nf)
        acc[mf][nf] = __builtin_amdgcn_mfma_f32_16x16x32_bf16(af[mf], bfr[nf], acc[mf][nf], 0, 0, 0);
    __builtin_amdgcn_s_setprio(0);
    if (t < 15) {
      *(short8*)&As[cur^1][rA][c8]      = merge8(pa0, pa1, rlp);
      *(short8*)&Bs[cur^1][rA][c8]      = pb0;
      *(short8*)&Bs[cur^1][64 + rA][c8] = pb1;
      if (t < 14) {
        const int kc = (t + 2) * 32;
        pa0 = *(const short8*)(A0 + kc);
        pa1 = *(const short8*)(A1 + kc);
        pb0 = *(const short8*)(Br0 + kc);
        pb1 = *(const short8*)(Br1 + kc);
        const int h2 = (t + 2) >> 1;
        rlp = rcp_raw(lp0[h2*NS] + lp1[h2*NS]);
      }
      __syncthreads();
    }
  }
  const int mw = m0 + wr*32, cw = n0 + wc*64;
  #pragma unroll
  for (int nf = 0; nf < 4; ++nf) {
    const int d = cw + nf*16 + (lane & 15);
    const float bo = bout[d];
    #pragma unroll
    for (int mf = 0; mf < 2; ++mf) {
      const int mb = mw + mf*16 + (lane >> 4)*4;
      const int bb = mb >> 11, n = mb & (NS-1);
      f32x4 res;
      #pragma unroll
      for (int r = 0; r < 4; ++r)
        res[r] = acc[mf][nf][r] + bf2f(xn[(size_t)(mb + r)*DIM + d]) + bo;
      *(f32x4*)&out[((size_t)bb*DIM + d)*NS + n] = res;
    }
  }
}

extern "C" void kernel_launch(void* const* d_in, const int* in_sizes, int n_in,
                              void* d_out, int out_size, void* d_ws, size_t ws_size,
                              hipStream_t stream) {
  (void)in_sizes; (void)n_in; (void)out_size; (void)ws_size;
  const float* x     = (const float*)d_in[0];
  const float* gamma = (const float*)d_in[1];
  const float* beta  = (const float*)d_in[2];
  const float* Wq    = (const float*)d_in[3];
  const float* Wkv   = (const float*)d_in[4];
  const float* Wout  = (const float*)d_in[5];
  const float* bout  = (const float*)d_in[6];
  float* out = (float*)d_out;
  char* ws = (char*)d_ws;
  unsigned short* xn    = (unsigned short*)(ws);                         // 8 MB
  unsigned short* qb    = (unsigned short*)(ws + (size_t)(8<<20));       // 8 MB
  unsigned short* kb    = (unsigned short*)(ws + (size_t)(16<<20));      // 2 MB
  unsigned short* vb    = (unsigned short*)(ws + (size_t)(18<<20));      // 2 MB (V^T)
  unsigned short* op0   = (unsigned short*)(ws + (size_t)(20<<20));      // 8 MB (half-0 partial)
  unsigned short* op1   = (unsigned short*)(ws + (size_t)(28<<20));      // 8 MB (half-1 partial)
  unsigned short* wqkvt = (unsigned short*)(ws + (size_t)(36<<20));      // 768 KB
  unsigned short* woutt = (unsigned short*)(ws + (size_t)(36<<20) + 786432);           // 512 KB
  float* tabs           = (float*)(ws + (size_t)(36<<20) + 786432 + 524288);           // 1 MB
  float* lp             = (float*)(ws + (size_t)(36<<20) + 786432 + 524288 + 1048576); // 512 KB

  lnprep_kernel<<<dim3(424), dim3(256), 0, stream>>>(x, gamma, beta, Wq, Wkv, Wout,
                                                     xn, wqkvt, woutt, tabs);
  qkv_kernel<<<dim3(128, 6), dim3(256), 0, stream>>>(xn, wqkvt, tabs, qb, kb, vb);
  attn_kernel<<<dim3(512), dim3(512), 0, stream>>>(qb, kb, vb, op0, op1, lp);
  out_kernel<<<dim3(128, 4), dim3(256), 0, stream>>>(op0, op1, lp, woutt, xn, bout, out);
}